// Round 3
// baseline (191.153 us; speedup 1.0000x reference)
//
#include <hip/hip_runtime.h>

#define N_PTS 128
#define EPS_F 1e-10f
#define FAR_F 1e10f

// DPP ctrl encodings (gfx9/CDNA):
//   ROW_SHR1=0x111 SHR2=0x112 SHR4=0x114 SHR8=0x118
//   ROW_BCAST15=0x142   WAVE_SHL1=0x130   WAVE_SHR1=0x138
template<int CTRL, int ROW_MASK>
__device__ __forceinline__ float dpp_mov(float src, float old) {
    union { float f; int i; } s, o, r;
    s.f = src; o.f = old;
    r.i = __builtin_amdgcn_update_dpp(o.i, s.i, CTRL, ROW_MASK, 0xF, false);
    return r.f;
}

// Sum over each 32-lane half-wave; totals land in lanes 31 and 63.
__device__ __forceinline__ float half32_reduce_add(float x) {
    x += dpp_mov<0x111, 0xF>(x, 0.0f);
    x += dpp_mov<0x112, 0xF>(x, 0.0f);
    x += dpp_mov<0x114, 0xF>(x, 0.0f);
    x += dpp_mov<0x118, 0xF>(x, 0.0f);
    x += dpp_mov<0x142, 0xA>(x, 0.0f);  // row_bcast15 -> rows 1,3
    return x;
}

// Half-wave (32 lanes) per ray; lane owns 4 consecutive points.
// All loads are dwordx4 (16 B/lane) -> 2x bytes in flight vs dwordx2 version.
__global__ __launch_bounds__(256) void volrend_kernel(
        const float* __restrict__ density,
        const float* __restrict__ feature,
        const float* __restrict__ depth,
        float* __restrict__ out, int n_rays) {
    const int lane = threadIdx.x & 63;
    const int hl   = lane & 31;                                 // lane in half
    const int wave = (blockIdx.x * 256 + threadIdx.x) >> 6;
    const int ray  = wave * 2 + (lane >> 5);                    // 2 rays / wave

    // Fully-used vector loads: density/depth 512 B per half, feature 1536 B.
    const float4 dns = ((const float4*)(density + (size_t)ray * N_PTS))[hl];
    const float4 z   = ((const float4*)(depth   + (size_t)ray * N_PTS))[hl];
    const float4* fp = (const float4*)(feature + (size_t)ray * (N_PTS * 3));
    const float4 fa = fp[hl * 3 + 0];   // p0.rgb, p1.r
    const float4 fb = fp[hl * 3 + 1];   // p1.gb, p2.rg
    const float4 fc = fp[hl * 3 + 2];   // p2.b, p3.rgb

    // deltas: within-lane diffs + next lane's first depth (wave_shl1).
    float nz = dpp_mov<0x130, 0xF>(z.x, 0.0f);                  // lane i <- i+1
    float d0 = z.y - z.x;
    float d1 = z.z - z.y;
    float d2 = z.w - z.z;
    float d3 = (hl == 31) ? FAR_F : (nz - z.w);                 // ray boundary

    float e0 = __expf(-d0 * dns.x), e1 = __expf(-d1 * dns.y);
    float e2 = __expf(-d2 * dns.z), e3 = __expf(-d3 * dns.w);
    float f0 = e0 + EPS_F, f1 = e1 + EPS_F, f2 = e2 + EPS_F, f3 = e3 + EPS_F;
    float a0 = 1.0f - e0,  a1 = 1.0f - e1,  a2 = 1.0f - e2,  a3 = 1.0f - e3;

    // Inclusive product-scan of per-lane factor over each 32-lane half.
    float p = (f0 * f1) * (f2 * f3);
    p *= dpp_mov<0x111, 0xF>(p, 1.0f);
    p *= dpp_mov<0x112, 0xF>(p, 1.0f);
    p *= dpp_mov<0x114, 0xF>(p, 1.0f);
    p *= dpp_mov<0x118, 0xF>(p, 1.0f);
    p *= dpp_mov<0x142, 0xA>(p, 1.0f);  // row_bcast15 -> rows 1,3
    // Exclusive: T entering point 4*hl. Lane 0/32 (hl==0) -> identity.
    float T0 = dpp_mov<0x138, 0xF>(p, 1.0f);                    // wave_shr:1
    T0 = (hl == 0) ? 1.0f : T0;

    float w0 = T0 * a0; float T1 = T0 * f0;
    float w1 = T1 * a1; float T2 = T1 * f1;
    float w2 = T2 * a2; float T3 = T2 * f2;
    float w3 = T3 * a3;

    // Per-lane partials, reduced over each half (VALU pipe only).
    float rx = half32_reduce_add(w0 * fa.x + w1 * fa.w + w2 * fb.z + w3 * fc.y);
    float ry = half32_reduce_add(w0 * fa.y + w1 * fb.x + w2 * fb.w + w3 * fc.z);
    float rz = half32_reduce_add(w0 * fa.z + w1 * fb.y + w2 * fc.x + w3 * fc.w);
    float dd = half32_reduce_add(w0 * z.x  + w1 * z.y  + w2 * z.z  + w3 * z.w);

    if (hl == 31) {   // lanes 31 and 63 hold their ray's totals
        float* o  = out + (size_t)ray * 3;
        o[0] = rx; o[1] = ry; o[2] = rz;
        float* od = out + (size_t)n_rays * 3 + (size_t)ray * 3;
        od[0] = dd; od[1] = dd; od[2] = dd;
    }
}

extern "C" void kernel_launch(void* const* d_in, const int* in_sizes, int n_in,
                              void* d_out, int out_size, void* d_ws, size_t ws_size,
                              hipStream_t stream) {
    const float* density = (const float*)d_in[0];
    const float* feature = (const float*)d_in[1];
    const float* depth   = (const float*)d_in[2];
    float* out = (float*)d_out;
    const int n_rays = in_sizes[0] / N_PTS;     // 65536
    // 2 rays per wave, 4 waves per block -> 8 rays per block
    const int blocks = (n_rays + 7) / 8;        // 8192
    volrend_kernel<<<blocks, 256, 0, stream>>>(density, feature, depth, out, n_rays);
}